// Round 1
// baseline (1515.102 us; speedup 1.0000x reference)
//
#include <hip/hip_runtime.h>

// VQ-VAE forward on MI355X. Dims hard-coded from reference:
// B=8 T=4096 -> N=32768 tokens, D=512, M=1024 codes, H=512.
// Outputs flat: quantized[16777216] loss[32768] perplexity[1]
//               new_embedding[524288] new_count[1024] new_weight[524288]

#define N_TOK 32768

__device__ __forceinline__ float waveSum(float v) {
#pragma unroll
    for (int off = 32; off > 0; off >>= 1) v += __shfl_down(v, off, 64);
    return v;  // valid in lane 0
}

// ---------------- e_sq[m] = sum_k E[m][k]^2 ----------------
__global__ __launch_bounds__(256) void esq_kernel(const float* __restrict__ E,
                                                  float* __restrict__ e_sq) {
    int lane = threadIdx.x & 63;
    int m = (blockIdx.x << 2) + (threadIdx.x >> 6);
    const float* row = E + ((size_t)m << 9);
    float s = 0.f;
#pragma unroll
    for (int i = 0; i < 8; ++i) { float v = row[lane + (i << 6)]; s += v * v; }
    s = waveSum(s);
    if (lane == 0) e_sq[m] = s;
}

// ---------------- per-row LN stats (rows of length 512) ----------------
__global__ __launch_bounds__(256) void lnstats_kernel(const float* __restrict__ X,
                                                      float* __restrict__ mu,
                                                      float* __restrict__ rs) {
    int lane = threadIdx.x & 63;
    int n = (blockIdx.x << 2) + (threadIdx.x >> 6);
    const float* row = X + ((size_t)n << 9);
    float s = 0.f, ss = 0.f;
#pragma unroll
    for (int i = 0; i < 8; ++i) { float v = row[lane + (i << 6)]; s += v; ss += v * v; }
    s = waveSum(s); ss = waveSum(ss);
    if (lane == 0) {
        float m = s * (1.f / 512.f);
        float var = ss * (1.f / 512.f) - m * m;
        mu[n] = m;
        rs[n] = rsqrtf(var + 1e-5f);
    }
}

// ---------------- distance GEMM + fused argmin ----------------
// dist = e_sq[m] - 2*x.e (x_sq constant per row -> argmin unchanged).
// Pack (sortable-dist, m) into u64; atomicMin => min dist, tie -> smallest m
// (matches jnp.argmin first-occurrence tie rule).
__device__ __forceinline__ unsigned long long packDist(float d, int m) {
    unsigned u = __float_as_uint(d);
    u = (u & 0x80000000u) ? ~u : (u | 0x80000000u);
    return ((unsigned long long)u << 32) | (unsigned)m;
}

__global__ __launch_bounds__(256) void dist_argmin_kernel(
        const float* __restrict__ X, const float* __restrict__ E,
        const float* __restrict__ e_sq, unsigned long long* __restrict__ minpack) {
    __shared__ float As[64][33];  // +1 pad -> 2-way max bank aliasing (free)
    __shared__ float Bs[64][33];
    int tid = threadIdx.x;
    int ty = tid >> 4, tx = tid & 15;       // 16x16 threads, 4x4 acc each
    int row0 = blockIdx.x << 6, m0 = blockIdx.y << 6;
    float acc[4][4] = {};
    int lr = tid >> 2, lc = (tid & 3) << 3; // staging: 8 consecutive floats/thread

    for (int k0 = 0; k0 < 512; k0 += 32) {
        const float* xa = X + (((size_t)(row0 + lr)) << 9) + k0 + lc;
        const float* ea = E + (((size_t)(m0 + lr)) << 9) + k0 + lc;
        float4 a0 = *(const float4*)xa, a1 = *(const float4*)(xa + 4);
        float4 b0 = *(const float4*)ea, b1 = *(const float4*)(ea + 4);
        As[lr][lc + 0] = a0.x; As[lr][lc + 1] = a0.y; As[lr][lc + 2] = a0.z; As[lr][lc + 3] = a0.w;
        As[lr][lc + 4] = a1.x; As[lr][lc + 5] = a1.y; As[lr][lc + 6] = a1.z; As[lr][lc + 7] = a1.w;
        Bs[lr][lc + 0] = b0.x; Bs[lr][lc + 1] = b0.y; Bs[lr][lc + 2] = b0.z; Bs[lr][lc + 3] = b0.w;
        Bs[lr][lc + 4] = b1.x; Bs[lr][lc + 5] = b1.y; Bs[lr][lc + 6] = b1.z; Bs[lr][lc + 7] = b1.w;
        __syncthreads();
#pragma unroll 8
        for (int kk = 0; kk < 32; ++kk) {
            float av[4], bv[4];
#pragma unroll
            for (int i = 0; i < 4; ++i) av[i] = As[(ty << 2) + i][kk];
#pragma unroll
            for (int j = 0; j < 4; ++j) bv[j] = Bs[(tx << 2) + j][kk];
#pragma unroll
            for (int i = 0; i < 4; ++i)
#pragma unroll
                for (int j = 0; j < 4; ++j) acc[i][j] += av[i] * bv[j];
        }
        __syncthreads();
    }
#pragma unroll
    for (int i = 0; i < 4; ++i) {
        int n = row0 + (ty << 2) + i;
        unsigned long long best = ~0ULL;
#pragma unroll
        for (int j = 0; j < 4; ++j) {
            int m = m0 + (tx << 2) + j;
            float d = e_sq[m] - 2.f * acc[i][j];
            unsigned long long p = packDist(d, m);
            if (p < best) best = p;
        }
        // reduce across the 16 tx lanes of this row (width-16 xor shuffle)
#pragma unroll
        for (int off = 8; off > 0; off >>= 1) {
            unsigned long long q = __shfl_xor(best, off, 16);
            if (q < best) best = q;
        }
        if (tx == 0) atomicMin(&minpack[n], best);
    }
}

// ---------------- gather quantized + scatter counts/dw + vq term ----------------
__global__ __launch_bounds__(256) void gather_kernel(
        const float* __restrict__ X, const float* __restrict__ E,
        const unsigned long long* __restrict__ minpack,
        float* __restrict__ out_q, float* __restrict__ counts,
        float* __restrict__ dw, float* __restrict__ vqsum) {
    int lane = threadIdx.x & 63;
    int n = (blockIdx.x << 2) + (threadIdx.x >> 6);
    int idx = (int)(minpack[n] & 0xFFFFFFFFULL);
    if (lane == 0) atomicAdd(&counts[idx], 1.0f);
    const float* xr = X + ((size_t)n << 9);
    const float* er = E + ((size_t)idx << 9);
    float s = 0.f;
#pragma unroll
    for (int i = 0; i < 8; ++i) {
        int c = lane + (i << 6);
        float xv = xr[c], q = er[c];
        out_q[((size_t)n << 9) + c] = q;  // quantized_st == quantized numerically
        atomicAdd(&dw[((size_t)idx << 9) + c], xv);
        float dlt = xv - q;
        s += dlt * dlt;
    }
    s = waveSum(s);
    if (lane == 0) vqsum[n] = 0.25f * s;  // COMMIT * sum_d (x-q)^2
}

// ---------------- GEMM1: h = relu(ln1(x)) @ W1  (LN fused into A staging) ----------------
__global__ __launch_bounds__(256) void gemm1_kernel(
        const float* __restrict__ X, const float* __restrict__ W1,
        const float* __restrict__ mu1, const float* __restrict__ rs1,
        const float* __restrict__ g1, const float* __restrict__ b1,
        float* __restrict__ Hout) {
    __shared__ float As[16][512];  // inner reads are wave-uniform broadcasts
    int tid = threadIdx.x;
    int n0 = blockIdx.x << 4;
    int c = tid << 1;
    float gg0 = g1[c], gg1 = g1[c + 1], bb0 = b1[c], bb1 = b1[c + 1];
#pragma unroll
    for (int r = 0; r < 16; ++r) {
        int n = n0 + r;
        float m = mu1[n], rr = rs1[n];
        float2 xv = *(const float2*)(X + ((size_t)n << 9) + c);
        As[r][c]     = fmaxf((xv.x - m) * rr * gg0 + bb0, 0.f);
        As[r][c + 1] = fmaxf((xv.y - m) * rr * gg1 + bb1, 0.f);
    }
    __syncthreads();
    int tx = tid & 127, ty = tid >> 7;  // 128 col-groups x 2 token-halves
    float acc[8][4] = {};
#pragma unroll 4
    for (int k = 0; k < 512; ++k) {
        float4 w = *(const float4*)(W1 + ((size_t)k << 9) + (tx << 2));
#pragma unroll
        for (int t = 0; t < 8; ++t) {
            float a = As[(ty << 3) + t][k];
            acc[t][0] += a * w.x; acc[t][1] += a * w.y;
            acc[t][2] += a * w.z; acc[t][3] += a * w.w;
        }
    }
#pragma unroll
    for (int t = 0; t < 8; ++t) {
        int n = n0 + (ty << 3) + t;
        float4 o; o.x = acc[t][0]; o.y = acc[t][1]; o.z = acc[t][2]; o.w = acc[t][3];
        *(float4*)(Hout + ((size_t)n << 9) + (tx << 2)) = o;
    }
}

// ---------------- GEMM2 + fused log_softmax CE; logits never materialized ----------------
__global__ __launch_bounds__(256) void gemm2_ce_kernel(
        const float* __restrict__ Hh, const float* __restrict__ W2,
        const float* __restrict__ mu2, const float* __restrict__ rs2,
        const float* __restrict__ g2, const float* __restrict__ b2,
        const int* __restrict__ mask, const int* __restrict__ labels,
        const float* __restrict__ vqsum, float* __restrict__ loss_out) {
    __shared__ float As[16][512];
    __shared__ float red[4];
    __shared__ float labLogit[16];
    int tid = threadIdx.x;
    int n0 = blockIdx.x << 4;
    int c = tid << 1;
    float gg0 = g2[c], gg1 = g2[c + 1], bb0 = b2[c], bb1 = b2[c + 1];
#pragma unroll
    for (int r = 0; r < 16; ++r) {
        int n = n0 + r;
        float m = mu2[n], rr = rs2[n];
        float2 xv = *(const float2*)(Hh + ((size_t)n << 9) + c);
        As[r][c]     = fmaxf((xv.x - m) * rr * gg0 + bb0, 0.f);
        As[r][c + 1] = fmaxf((xv.y - m) * rr * gg1 + bb1, 0.f);
    }
    __syncthreads();
    float acc[16][4] = {};  // thread owns cols 4*tid..4*tid+3, all 16 tokens
#pragma unroll 2
    for (int k = 0; k < 512; ++k) {
        float4 w = *(const float4*)(W2 + ((size_t)k << 10) + (tid << 2));
#pragma unroll
        for (int t = 0; t < 16; ++t) {
            float a = As[t][k];
            acc[t][0] += a * w.x; acc[t][1] += a * w.y;
            acc[t][2] += a * w.z; acc[t][3] += a * w.w;
        }
    }
    int lane = tid & 63, wid = tid >> 6;
    for (int t = 0; t < 16; ++t) {
        // block max
        float lm = fmaxf(fmaxf(acc[t][0], acc[t][1]), fmaxf(acc[t][2], acc[t][3]));
#pragma unroll
        for (int off = 32; off > 0; off >>= 1) lm = fmaxf(lm, __shfl_down(lm, off, 64));
        if (lane == 0) red[wid] = lm;
        __syncthreads();
        float mx = fmaxf(fmaxf(red[0], red[1]), fmaxf(red[2], red[3]));
        __syncthreads();
        // block sum-exp
        float ls = expf(acc[t][0] - mx) + expf(acc[t][1] - mx) +
                   expf(acc[t][2] - mx) + expf(acc[t][3] - mx);
#pragma unroll
        for (int off = 32; off > 0; off >>= 1) ls += __shfl_down(ls, off, 64);
        if (lane == 0) red[wid] = ls;
        __syncthreads();
        float se = red[0] + red[1] + red[2] + red[3];
        int n = n0 + t;
        int mk = mask[n];
        int lab = labels[n];
        int safe = mk ? 0 : lab;
        if (tid == (safe >> 2)) {
            int j = safe & 3;
            float v = (j == 0) ? acc[t][0] : (j == 1) ? acc[t][1]
                    : (j == 2) ? acc[t][2] : acc[t][3];
            labLogit[t] = v;
        }
        __syncthreads();
        if (tid == 0) {
            float ce = -(labLogit[t] - mx - logf(se));
            loss_out[n] = (mk ? 0.f : ce) + vqsum[n];
        }
        __syncthreads();
    }
}

// ---------------- EMA count smoothing + perplexity (single block) ----------------
__global__ __launch_bounds__(1024) void codebook_kernel(
        const float* __restrict__ ema_count, const float* __restrict__ counts,
        float* __restrict__ out_perp, float* __restrict__ out_newcount) {
    __shared__ float red[16];
    int tid = threadIdx.x;
    int lane = tid & 63, wid = tid >> 6;
    float cnt = counts[tid];
    float raw = 0.999f * ema_count[tid] + 0.001f * cnt;
    float v = waveSum(raw);
    if (lane == 0) red[wid] = v;
    __syncthreads();
    float nsum = 0.f;
#pragma unroll
    for (int i = 0; i < 16; ++i) nsum += red[i];
    __syncthreads();
    float p = cnt * (1.f / 32768.f);
    float e = p * logf(p + 1e-10f);
    e = waveSum(e);
    if (lane == 0) red[wid] = e;
    __syncthreads();
    float ent = 0.f;
#pragma unroll
    for (int i = 0; i < 16; ++i) ent += red[i];
    float nc = (raw + 1e-5f) / (nsum + 1024.f * 1e-5f) * nsum;
    out_newcount[tid] = nc;
    if (tid == 0) out_perp[0] = expf(-ent);
}

// ---------------- new_weight / new_embedding ----------------
__global__ __launch_bounds__(256) void newweight_kernel(
        const float* __restrict__ ema_weight, const float* __restrict__ dw,
        const float* __restrict__ newcount, float* __restrict__ out_neww,
        float* __restrict__ out_newemb) {
    int i = (blockIdx.x << 8) + threadIdx.x;
    float nw = 0.999f * ema_weight[i] + 0.001f * dw[i];
    out_neww[i] = nw;
    out_newemb[i] = nw / newcount[i >> 9];
}

extern "C" void kernel_launch(void* const* d_in, const int* in_sizes, int n_in,
                              void* d_out, int out_size, void* d_ws, size_t ws_size,
                              hipStream_t stream) {
    const float* X          = (const float*)d_in[0];
    const int*   mask       = (const int*)d_in[1];   // bool -> int32 per harness convention
    const int*   labels     = (const int*)d_in[2];
    const float* E          = (const float*)d_in[3];
    const float* ema_count  = (const float*)d_in[4];
    const float* ema_weight = (const float*)d_in[5];
    const float* g1 = (const float*)d_in[6];
    const float* b1 = (const float*)d_in[7];
    const float* W1 = (const float*)d_in[8];
    const float* g2 = (const float*)d_in[9];
    const float* b2 = (const float*)d_in[10];
    const float* W2 = (const float*)d_in[11];

    float* out = (float*)d_out;
    float* out_q        = out;              // 16777216
    float* out_loss     = out + 16777216;   // 32768
    float* out_perp     = out + 16809984;   // 1
    float* out_newemb   = out + 16809985;   // 524288
    float* out_newcount = out + 17334273;   // 1024
    float* out_neww     = out + 17335297;   // 524288

    float* w = (float*)d_ws;                // ~70.1 MB total
    float* mu1 = w;    w += 32768;
    float* rs1 = w;    w += 32768;
    float* mu2 = w;    w += 32768;
    float* rs2 = w;    w += 32768;
    float* vqsum = w;  w += 32768;
    float* e_sq = w;   w += 1024;
    float* counts = w; w += 1024;
    float* dwbuf = w;  w += 524288;         // contiguous with counts for one memset
    float* Hbuf = w;   w += 16777216;
    unsigned long long* minpack = (unsigned long long*)w;

    hipMemsetAsync(counts, 0, (1024 + 524288) * sizeof(float), stream);
    hipMemsetAsync(minpack, 0xFF, (size_t)N_TOK * sizeof(unsigned long long), stream);

    esq_kernel<<<256, 256, 0, stream>>>(E, e_sq);
    lnstats_kernel<<<8192, 256, 0, stream>>>(X, mu1, rs1);
    dist_argmin_kernel<<<dim3(512, 16), 256, 0, stream>>>(X, E, e_sq, minpack);
    gather_kernel<<<8192, 256, 0, stream>>>(X, E, minpack, out_q, counts, dwbuf, vqsum);
    gemm1_kernel<<<2048, 256, 0, stream>>>(X, W1, mu1, rs1, g1, b1, Hbuf);
    lnstats_kernel<<<8192, 256, 0, stream>>>(Hbuf, mu2, rs2);
    gemm2_ce_kernel<<<2048, 256, 0, stream>>>(Hbuf, W2, mu2, rs2, g2, b2,
                                              mask, labels, vqsum, out_loss);
    codebook_kernel<<<1, 1024, 0, stream>>>(ema_count, counts, out_perp, out_newcount);
    newweight_kernel<<<2048, 256, 0, stream>>>(ema_weight, dwbuf, out_newcount,
                                               out_neww, out_newemb);
}

// Round 2
// 604.448 us; speedup vs baseline: 2.5066x; 2.5066x over previous
//
#include <hip/hip_runtime.h>

// VQ-VAE forward on MI355X (gfx950). N=32768 tokens, D=512, M=1024, H=512.
// R2: all three GEMMs on bf16 MFMA. Distance GEMM uses hi/lo bf16 split
// (3 MFMA passes) so argmin precision stays at fp32 level. CE fused into
// gemm2 (block = 32 tokens x all 1024 codes). dw scatter via ballot-ownership
// kernel instead of global atomics.

#define N_TOK 32768

typedef __attribute__((ext_vector_type(8))) short short8;   // 8 bf16 = 4 VGPR
typedef __attribute__((ext_vector_type(4))) float f32x4;

__device__ __forceinline__ f32x4 mfma16(short8 a, short8 b, f32x4 c) {
    return __builtin_amdgcn_mfma_f32_16x16x32_bf16(a, b, c, 0, 0, 0);
}

__device__ __forceinline__ void gl_lds16(const void* g, void* l) {
    __builtin_amdgcn_global_load_lds(
        (const __attribute__((address_space(1))) void*)g,
        (__attribute__((address_space(3))) void*)l, 16, 0, 0);
}

__device__ __forceinline__ unsigned short f2bf(float x) {   // RNE fp32->bf16
    unsigned u = __float_as_uint(x);
    u += 0x7fffu + ((u >> 16) & 1u);
    return (unsigned short)(u >> 16);
}
__device__ __forceinline__ float bf2f(unsigned short h) {
    return __uint_as_float(((unsigned)h) << 16);
}

__device__ __forceinline__ float waveSum(float v) {
#pragma unroll
    for (int off = 32; off > 0; off >>= 1) v += __shfl_down(v, off, 64);
    return v;  // lane 0
}
__device__ __forceinline__ float xorSum(float v) {
#pragma unroll
    for (int off = 1; off < 64; off <<= 1) v += __shfl_xor(v, off);
    return v;  // all lanes
}

// Stage one 128x32 bf16 tile into LDS, chunk-swizzled layout [kb][128][8]
// (kb = 16B chunk of K). LDS dest is lane-linear per wave (global_load_lds
// requirement); swizzle is applied on the *global* source address.
__device__ __forceinline__ void stage_tile128(const unsigned short* __restrict__ src,
                                              int r0, int k0, short* lds,
                                              int w, int lane) {
#pragma unroll
    for (int iss = 0; iss < 2; ++iss) {
        int L = (w << 11) + (iss << 10) + (lane << 4);  // byte offset in 8KB tile
        int kb = L >> 11, m = (L >> 4) & 127;
        gl_lds16(src + (((size_t)(r0 + m)) << 9) + k0 + (kb << 3), (char*)lds + L);
    }
}

// ---------------- prep: X -> Xh,Xl (split bf16) + A1 = bf16(relu(ln1(x))) ----
__global__ __launch_bounds__(256) void prep_x_kernel(
        const float* __restrict__ X, const float* __restrict__ g,
        const float* __restrict__ b, unsigned short* __restrict__ Xh,
        unsigned short* __restrict__ Xl, unsigned short* __restrict__ A1) {
    int lane = threadIdx.x & 63;
    int n = (blockIdx.x << 2) + (threadIdx.x >> 6);
    const float* row = X + ((size_t)n << 9);
    float v[8]; float s = 0.f, ss = 0.f;
#pragma unroll
    for (int i = 0; i < 8; ++i) { v[i] = row[lane + (i << 6)]; s += v[i]; ss += v[i] * v[i]; }
    s = xorSum(s); ss = xorSum(ss);
    float mu = s * (1.f / 512.f);
    float rs = rsqrtf(ss * (1.f / 512.f) - mu * mu + 1e-5f);
#pragma unroll
    for (int i = 0; i < 8; ++i) {
        int c = lane + (i << 6);
        size_t o = ((size_t)n << 9) + c;
        float x = v[i];
        unsigned short h = f2bf(x);
        Xh[o] = h;
        Xl[o] = f2bf(x - bf2f(h));
        float a = fmaxf((x - mu) * rs * g[c] + b[c], 0.f);
        A1[o] = f2bf(a);
    }
}

// ---------------- prep: Hb(bf16) -> A2 = bf16(relu(ln2(h))) ----------------
__global__ __launch_bounds__(256) void prep_h_kernel(
        const unsigned short* __restrict__ Hb, const float* __restrict__ g,
        const float* __restrict__ b, unsigned short* __restrict__ A2) {
    int lane = threadIdx.x & 63;
    int n = (blockIdx.x << 2) + (threadIdx.x >> 6);
    const unsigned short* row = Hb + ((size_t)n << 9);
    float v[8]; float s = 0.f, ss = 0.f;
#pragma unroll
    for (int i = 0; i < 8; ++i) { v[i] = bf2f(row[lane + (i << 6)]); s += v[i]; ss += v[i] * v[i]; }
    s = xorSum(s); ss = xorSum(ss);
    float mu = s * (1.f / 512.f);
    float rs = rsqrtf(ss * (1.f / 512.f) - mu * mu + 1e-5f);
#pragma unroll
    for (int i = 0; i < 8; ++i) {
        int c = lane + (i << 6);
        float a = fmaxf((v[i] - mu) * rs * g[c] + b[c], 0.f);
        A2[((size_t)n << 9) + c] = f2bf(a);
    }
}

// ---------------- prep: E -> Eh,El + e_sq ----------------
__global__ __launch_bounds__(256) void prep_e_kernel(
        const float* __restrict__ E, unsigned short* __restrict__ Eh,
        unsigned short* __restrict__ El, float* __restrict__ e_sq) {
    int lane = threadIdx.x & 63;
    int m = (blockIdx.x << 2) + (threadIdx.x >> 6);
    const float* row = E + ((size_t)m << 9);
    float ss = 0.f;
#pragma unroll
    for (int i = 0; i < 8; ++i) {
        int c = lane + (i << 6);
        float x = row[c];
        ss += x * x;
        unsigned short h = f2bf(x);
        size_t o = ((size_t)m << 9) + c;
        Eh[o] = h;
        El[o] = f2bf(x - bf2f(h));
    }
    ss = xorSum(ss);
    if (lane == 0) e_sq[m] = ss;
}

// ---------------- prep: W[512][Nw] fp32 -> WT[Nw][512] bf16 ----------------
__global__ __launch_bounds__(256) void prep_wt_kernel(
        const float* __restrict__ W, unsigned short* __restrict__ WT, int Nw) {
    __shared__ float t[32][33];
    int n0 = blockIdx.x << 5, k0 = blockIdx.y << 5;
    int tx = threadIdx.x & 31, ty = threadIdx.x >> 5;
#pragma unroll
    for (int l = 0; l < 4; ++l)
        t[ty + (l << 3)][tx] = W[(size_t)(k0 + ty + (l << 3)) * Nw + n0 + tx];
    __syncthreads();
#pragma unroll
    for (int l = 0; l < 4; ++l)
        WT[(((size_t)(n0 + ty + (l << 3))) << 9) + k0 + tx] = f2bf(t[tx][ty + (l << 3)]);
}

// ---------------- distance MFMA (3-pass split) + fused argmin ----------------
__device__ __forceinline__ unsigned long long packDist(float d, int m) {
    unsigned u = __float_as_uint(d);
    u = (u & 0x80000000u) ? ~u : (u | 0x80000000u);
    return ((unsigned long long)u << 32) | (unsigned)m;
}

__global__ __launch_bounds__(256) void dist_mfma_kernel(
        const unsigned short* __restrict__ Xh, const unsigned short* __restrict__ Xl,
        const unsigned short* __restrict__ Eh, const unsigned short* __restrict__ El,
        const float* __restrict__ e_sq, unsigned long long* __restrict__ minpack) {
    __shared__ __align__(16) short Ah[4096], Al[4096], Bh[4096], Bl[4096];
    int tid = threadIdx.x, lane = tid & 63, w = tid >> 6;
    int quad = lane >> 4, lanelo = lane & 15;
    int wm = w >> 1, wn = w & 1;
    int row0 = blockIdx.x << 7, m0 = blockIdx.y << 7;
    f32x4 acc[4][4];
#pragma unroll
    for (int i = 0; i < 4; ++i)
#pragma unroll
        for (int j = 0; j < 4; ++j) acc[i][j] = 0.f;

    for (int k0 = 0; k0 < 512; k0 += 32) {
        stage_tile128(Xh, row0, k0, Ah, w, lane);
        stage_tile128(Xl, row0, k0, Al, w, lane);
        stage_tile128(Eh, m0, k0, Bh, w, lane);
        stage_tile128(El, m0, k0, Bl, w, lane);
        __syncthreads();
        short8 ah[4], alr[4], bh[4], blr[4];
#pragma unroll
        for (int i = 0; i < 4; ++i) {
            int m = (wm << 6) + (i << 4) + lanelo;
            ah[i]  = *(const short8*)&Ah[(quad << 10) + (m << 3)];
            alr[i] = *(const short8*)&Al[(quad << 10) + (m << 3)];
        }
#pragma unroll
        for (int j = 0; j < 4; ++j) {
            int n = (wn << 6) + (j << 4) + lanelo;
            bh[j]  = *(const short8*)&Bh[(quad << 10) + (n << 3)];
            blr[j] = *(const short8*)&Bl[(quad << 10) + (n << 3)];
        }
#pragma unroll
        for (int i = 0; i < 4; ++i)
#pragma unroll
            for (int j = 0; j < 4; ++j) {
                acc[i][j] = mfma16(ah[i],  bh[j],  acc[i][j]);
                acc[i][j] = mfma16(alr[i], bh[j],  acc[i][j]);
                acc[i][j] = mfma16(ah[i],  blr[j], acc[i][j]);
            }
        __syncthreads();
    }

    float esq[4];
#pragma unroll
    for (int j = 0; j < 4; ++j) esq[j] = e_sq[m0 + (wn << 6) + (j << 4) + lanelo];
#pragma unroll
    for (int i = 0; i < 4; ++i)
#pragma unroll
        for (int r = 0; r < 4; ++r) {
            unsigned long long best = ~0ULL;
#pragma unroll
            for (int j = 0; j < 4; ++j) {
                int code = m0 + (wn << 6) + (j << 4) + lanelo;
                float d = esq[j] - 2.f * acc[i][j][r];
                unsigned long long p = packDist(d, code);
                if (p < best) best = p;
            }
#pragma unroll
            for (int off = 1; off < 16; off <<= 1) {
                unsigned long long q = __shfl_xor(best, off);
                if (q < best) best = q;
            }
            if (lanelo == 0) {
                int t = row0 + (wm << 6) + (i << 4) + (quad << 2) + r;
                atomicMin(&minpack[t], best);
            }
        }
}

// ---------------- gather quantized + counts + vq term ----------------
__global__ __launch_bounds__(256) void gather_kernel(
        const float* __restrict__ X, const float* __restrict__ E,
        const unsigned long long* __restrict__ minpack,
        float* __restrict__ out_q, float* __restrict__ counts,
        float* __restrict__ vqsum) {
    int lane = threadIdx.x & 63;
    int n = (blockIdx.x << 2) + (threadIdx.x >> 6);
    int idx = (int)(minpack[n] & 0xFFFFFFFFULL);
    if (lane == 0) atomicAdd(&counts[idx], 1.0f);
    const float* xr = X + ((size_t)n << 9);
    const float* er = E + ((size_t)idx << 9);
    float s = 0.f;
#pragma unroll
    for (int i = 0; i < 8; ++i) {
        int c = lane + (i << 6);
        float xv = xr[c], q = er[c];
        out_q[((size_t)n << 9) + c] = q;
        float dlt = xv - q;
        s += dlt * dlt;
    }
    s = waveSum(s);
    if (lane == 0) vqsum[n] = 0.25f * s;
}

// ---------------- dw[m] = sum of x rows assigned to code m (no atomics) ----
__global__ __launch_bounds__(256) void dw_kernel(
        const float* __restrict__ X, const unsigned long long* __restrict__ minpack,
        float* __restrict__ dw) {
    __shared__ float acc[4][512];
    int tid = threadIdx.x, lane = tid & 63, w = tid >> 6;
    int m = blockIdx.x;
    for (int c = lane; c < 512; c += 64) acc[w][c] = 0.f;
    for (int n0 = (w << 13); n0 < ((w + 1) << 13); n0 += 64) {
        int idx = (int)(minpack[n0 + lane] & 0xFFFFFFFFULL);
        unsigned long long hit = __ballot(idx == m);
        while (hit) {
            int t = __ffsll((unsigned long long)hit) - 1;
            hit &= hit - 1;
            const float* xr = X + ((size_t)(n0 + t) << 9);
#pragma unroll
            for (int i = 0; i < 8; ++i) acc[w][lane + (i << 6)] += xr[lane + (i << 6)];
        }
    }
    __syncthreads();
    for (int c = tid; c < 512; c += 256)
        dw[((size_t)m << 9) + c] = acc[0][c] + acc[1][c] + acc[2][c] + acc[3][c];
}

// ---------------- GEMM1 MFMA: Hb = bf16(A1 @ W1T^T) ----------------
__global__ __launch_bounds__(256) void gemm1_mfma_kernel(
        const unsigned short* __restrict__ A1, const unsigned short* __restrict__ W1T,
        unsigned short* __restrict__ Hb) {
    __shared__ __align__(16) short As[4096], Bs[4096];
    int tid = threadIdx.x, lane = tid & 63, w = tid >> 6;
    int quad = lane >> 4, lanelo = lane & 15;
    int wm = w >> 1, wn = w & 1;
    int row0 = blockIdx.x << 7, n0 = blockIdx.y << 7;
    f32x4 acc[4][4];
#pragma unroll
    for (int i = 0; i < 4; ++i)
#pragma unroll
        for (int j = 0; j < 4; ++j) acc[i][j] = 0.f;

    for (int k0 = 0; k0 < 512; k0 += 32) {
        stage_tile128(A1, row0, k0, As, w, lane);
        stage_tile128(W1T, n0, k0, Bs, w, lane);
        __syncthreads();
        short8 af[4], bf[4];
#pragma unroll
        for (int i = 0; i < 4; ++i) {
            int m = (wm << 6) + (i << 4) + lanelo;
            af[i] = *(const short8*)&As[(quad << 10) + (m << 3)];
        }
#pragma unroll
        for (int j = 0; j < 4; ++j) {
            int n = (wn << 6) + (j << 4) + lanelo;
            bf[j] = *(const short8*)&Bs[(quad << 10) + (n << 3)];
        }
#pragma unroll
        for (int i = 0; i < 4; ++i)
#pragma unroll
            for (int j = 0; j < 4; ++j) acc[i][j] = mfma16(af[i], bf[j], acc[i][j]);
        __syncthreads();
    }
#pragma unroll
    for (int i = 0; i < 4; ++i)
#pragma unroll
        for (int j = 0; j < 4; ++j)
#pragma unroll
            for (int r = 0; r < 4; ++r) {
                int row = row0 + (wm << 6) + (i << 4) + (quad << 2) + r;
                int col = n0 + (wn << 6) + (j << 4) + lanelo;
                Hb[((size_t)row << 9) + col] = f2bf(acc[i][j][r]);
            }
}

// ---------------- GEMM2 MFMA + fused CE: block = 32 tokens x all 1024 codes --
__global__ __launch_bounds__(256) void gemm2_ce_kernel(
        const unsigned short* __restrict__ A2, const unsigned short* __restrict__ W2T,
        const int* __restrict__ mask, const int* __restrict__ labels,
        const float* __restrict__ vqsum, float* __restrict__ loss_out) {
    __shared__ __align__(16) short As[16384];  // [64 kb][32 m][8] = 32 KB
    __shared__ float lmax[4][32], lsum[4][32], gmax[32], llab[32];
    __shared__ int slab[32], smask[32];
    int tid = threadIdx.x, lane = tid & 63, w = tid >> 6;
    int quad = lane >> 4, lanelo = lane & 15;
    int n0 = blockIdx.x << 5;
    if (tid < 32) {
        int mk = mask[n0 + tid];
        smask[tid] = mk;
        slab[tid] = mk ? 0 : labels[n0 + tid];
    }
#pragma unroll
    for (int iss = 0; iss < 8; ++iss) {   // stage A: full K resident
        int L = (w << 13) + (iss << 10) + (lane << 4);
        int kb = L >> 9, m = (L >> 4) & 31;
        gl_lds16(A2 + (((size_t)(n0 + m)) << 9) + (kb << 3), (char*)As + L);
    }
    __syncthreads();

    f32x4 acc0[16], acc1[16];
#pragma unroll
    for (int j = 0; j < 16; ++j) { acc0[j] = 0.f; acc1[j] = 0.f; }
    for (int k0 = 0; k0 < 512; k0 += 32) {
        int kb = (k0 >> 3) + quad;
        short8 a0 = *(const short8*)&As[(kb << 8) + (lanelo << 3)];
        short8 a1 = *(const short8*)&As[(kb << 8) + ((16 + lanelo) << 3)];
#pragma unroll
        for (int j = 0; j < 16; ++j) {
            int n = (w << 8) + (j << 4) + lanelo;
            short8 bf = *(const short8*)(W2T + ((size_t)n << 9) + k0 + (quad << 3));
            acc0[j] = mfma16(a0, bf, acc0[j]);
            acc1[j] = mfma16(a1, bf, acc1[j]);
        }
    }

    // label logit capture (unique owner lane/reg writes)
#pragma unroll
    for (int half = 0; half < 2; ++half)
#pragma unroll
        for (int j = 0; j < 16; ++j)
#pragma unroll
            for (int r = 0; r < 4; ++r) {
                int code = (w << 8) + (j << 4) + lanelo;
                int t = (half << 4) + (quad << 2) + r;
                float v = half ? acc1[j][r] : acc0[j][r];
                if (code == slab[t]) llab[t] = v;
            }
    // per-wave max over its 256 codes
#pragma unroll
    for (int half = 0; half < 2; ++half)
#pragma unroll
        for (int r = 0; r < 4; ++r) {
            float mx = -3.4e38f;
#pragma unroll
            for (int j = 0; j < 16; ++j) mx = fmaxf(mx, half ? acc1[j][r] : acc0[j][r]);
#pragma unroll
            for (int off = 1; off < 16; off <<= 1) mx = fmaxf(mx, __shfl_xor(mx, off));
            if (lanelo == 0) lmax[w][(half << 4) + (quad << 2) + r] = mx;
        }
    __syncthreads();
    if (tid < 32)
        gmax[tid] = fmaxf(fmaxf(lmax[0][tid], lmax[1][tid]),
                          fmaxf(lmax[2][tid], lmax[3][tid]));
    __syncthreads();
#pragma unroll
    for (int half = 0; half < 2; ++half)
#pragma unroll
        for (int r = 0; r < 4; ++r) {
            int t = (half << 4) + (quad << 2) + r;
            float gm = gmax[t];
            float s = 0.f;
#pragma unroll
            for (int j = 0; j < 16; ++j) s += expf((half ? acc1[j][r] : acc0[j][r]) - gm);
#pragma unroll
            for (int off = 1; off < 16; off <<= 1) s += __shfl_xor(s, off);
            if (lanelo == 0) lsum[w][t] = s;
        }
    __syncthreads();
    if (tid < 32) {
        float se = lsum[0][tid] + lsum[1][tid] + lsum[2][tid] + lsum[3][tid];
        int n = n0 + tid;
        float ce = -(llab[tid] - gmax[tid] - logf(se));
        loss_out[n] = (smask[tid] ? 0.f : ce) + vqsum[n];
    }
}

// ---------------- EMA count smoothing + perplexity ----------------
__global__ __launch_bounds__(1024) void codebook_kernel(
        const float* __restrict__ ema_count, const float* __restrict__ counts,
        float* __restrict__ out_perp, float* __restrict__ out_newcount) {
    __shared__ float red[16];
    int tid = threadIdx.x;
    int lane = tid & 63, wid = tid >> 6;
    float cnt = counts[tid];
    float raw = 0.999f * ema_count[tid] + 0.001f * cnt;
    float v = waveSum(raw);
    if (lane == 0) red[wid] = v;
    __syncthreads();
    float nsum = 0.f;
#pragma unroll
    for (int i = 0; i < 16; ++i) nsum += red[i];
    __syncthreads();
    float p = cnt * (1.f / 32768.f);
    float e = p * logf(p + 1e-10f);
    e = waveSum(e);
    if (lane == 0) red[wid] = e;
    __syncthreads();
    float ent = 0.f;
#pragma unroll
    for (int i = 0; i < 16; ++i) ent += red[i];
    float nc = (raw + 1e-5f) / (nsum + 1024.f * 1e-5f) * nsum;
    out_newcount[tid] = nc;
    if (tid == 0) out_perp[0] = expf(-ent);
}

__global__ __launch_bounds__(256) void newweight_kernel(
        const float* __restrict__ ema_weight, const float* __restrict__ dw,
        const float* __restrict__ newcount, float* __restrict__ out_neww,
        float* __restrict__ out_newemb) {
    int i = (blockIdx.x << 8) + threadIdx.x;
    float nw = 0.999f * ema_weight[i] + 0.001f * dw[i];
    out_neww[i] = nw;
    out_newemb[i] = nw / newcount[i >> 9];
}

extern "C" void kernel_launch(void* const* d_in, const int* in_sizes, int n_in,
                              void* d_out, int out_size, void* d_ws, size_t ws_size,
                              hipStream_t stream) {
    const float* X          = (const float*)d_in[0];
    const int*   mask       = (const int*)d_in[1];
    const int*   labels     = (const int*)d_in[2];
    const float* E          = (const float*)d_in[3];
    const float* ema_count  = (const float*)d_in[4];
    const float* ema_weight = (const float*)d_in[5];
    const float* g1 = (const float*)d_in[6];
    const float* b1 = (const float*)d_in[7];
    const float* W1 = (const float*)d_in[8];
    const float* g2 = (const float*)d_in[9];
    const float* b2 = (const float*)d_in[10];
    const float* W2 = (const float*)d_in[11];

    float* out = (float*)d_out;
    float* out_q        = out;              // 16777216
    float* out_loss     = out + 16777216;   // 32768
    float* out_perp     = out + 16809984;   // 1
    float* out_newemb   = out + 16809985;   // 524288
    float* out_newcount = out + 17334273;   // 1024
    float* out_neww     = out + 17335297;   // 524288

    float* w = (float*)d_ws;                // ~107 MB total
    float* vqsum = w;  w += 32768;
    float* e_sq = w;   w += 1024;
    float* counts = w; w += 1024;
    float* dwbuf = w;  w += 524288;
    unsigned long long* minpack = (unsigned long long*)w; w += 65536;
    unsigned short* Eh  = (unsigned short*)w; w += 262144;
    unsigned short* El  = (unsigned short*)w; w += 262144;
    unsigned short* W1T = (unsigned short*)w; w += 131072;
    unsigned short* W2T = (unsigned short*)w; w += 262144;
    unsigned short* Xh  = (unsigned short*)w; w += 8388608;
    unsigned short* Xl  = (unsigned short*)w; w += 8388608;
    unsigned short* A1  = (unsigned short*)w; w += 8388608;
    unsigned short* A2  = Xh;   // alias: Xh dead after dist
    unsigned short* Hb  = Xl;   // alias: Xl dead after dist

    hipMemsetAsync(counts, 0, 1024 * sizeof(float), stream);
    hipMemsetAsync(minpack, 0xFF, (size_t)N_TOK * sizeof(unsigned long long), stream);

    prep_e_kernel<<<256, 256, 0, stream>>>(E, Eh, El, e_sq);
    prep_wt_kernel<<<dim3(16, 16), 256, 0, stream>>>(W1, W1T, 512);
    prep_wt_kernel<<<dim3(32, 16), 256, 0, stream>>>(W2, W2T, 1024);
    prep_x_kernel<<<8192, 256, 0, stream>>>(X, g1, b1, Xh, Xl, A1);
    dist_mfma_kernel<<<dim3(256, 8), 256, 0, stream>>>(Xh, Xl, Eh, El, e_sq, minpack);
    gather_kernel<<<8192, 256, 0, stream>>>(X, E, minpack, out_q, counts, vqsum);
    dw_kernel<<<1024, 256, 0, stream>>>(X, minpack, dwbuf);
    gemm1_mfma_kernel<<<dim3(256, 4), 256, 0, stream>>>(A1, W1T, Hb);
    prep_h_kernel<<<8192, 256, 0, stream>>>(Hb, g2, b2, A2);
    gemm2_ce_kernel<<<1024, 256, 0, stream>>>(A2, W2T, mask, labels, vqsum, out_loss);
    codebook_kernel<<<1, 1024, 0, stream>>>(ema_count, counts, out_perp, out_newcount);
    newweight_kernel<<<2048, 256, 0, stream>>>(ema_weight, dwbuf, out_newcount,
                                               out_neww, out_newemb);
}

// Round 3
// 548.531 us; speedup vs baseline: 2.7621x; 1.1019x over previous
//
#include <hip/hip_runtime.h>

// VQ-VAE forward on MI355X (gfx950). N=32768 tokens, D=512, M=1024, H=512.
// R3: gemm2+CE restructured as chunked GEMM (gemm1 skeleton, 128x128 tiles,
// good occupancy) emitting per-chunk softmax partials (max, sumexp, label
// logit) to workspace + a tiny combine kernel. R2's fused version died at
// 11% occupancy (128 AGPR acc/lane -> 1 wave/SIMD).

#define N_TOK 32768

typedef __attribute__((ext_vector_type(8))) short short8;   // 8 bf16 = 4 VGPR
typedef __attribute__((ext_vector_type(4))) float f32x4;

__device__ __forceinline__ f32x4 mfma16(short8 a, short8 b, f32x4 c) {
    return __builtin_amdgcn_mfma_f32_16x16x32_bf16(a, b, c, 0, 0, 0);
}

__device__ __forceinline__ void gl_lds16(const void* g, void* l) {
    __builtin_amdgcn_global_load_lds(
        (const __attribute__((address_space(1))) void*)g,
        (__attribute__((address_space(3))) void*)l, 16, 0, 0);
}

__device__ __forceinline__ unsigned short f2bf(float x) {   // RNE fp32->bf16
    unsigned u = __float_as_uint(x);
    u += 0x7fffu + ((u >> 16) & 1u);
    return (unsigned short)(u >> 16);
}
__device__ __forceinline__ float bf2f(unsigned short h) {
    return __uint_as_float(((unsigned)h) << 16);
}

__device__ __forceinline__ float waveSum(float v) {
#pragma unroll
    for (int off = 32; off > 0; off >>= 1) v += __shfl_down(v, off, 64);
    return v;  // lane 0
}
__device__ __forceinline__ float xorSum(float v) {
#pragma unroll
    for (int off = 1; off < 64; off <<= 1) v += __shfl_xor(v, off);
    return v;  // all lanes
}

// Stage one 128x32 bf16 tile into LDS, chunk-swizzled layout [kb][128][8]
// (kb = 16B chunk of K). LDS dest is lane-linear per wave (global_load_lds
// requirement); swizzle is applied on the *global* source address.
__device__ __forceinline__ void stage_tile128(const unsigned short* __restrict__ src,
                                              int r0, int k0, short* lds,
                                              int w, int lane) {
#pragma unroll
    for (int iss = 0; iss < 2; ++iss) {
        int L = (w << 11) + (iss << 10) + (lane << 4);  // byte offset in 8KB tile
        int kb = L >> 11, m = (L >> 4) & 127;
        gl_lds16(src + (((size_t)(r0 + m)) << 9) + k0 + (kb << 3), (char*)lds + L);
    }
}

// ---------------- prep: X -> Xh,Xl (split bf16) + A1 = bf16(relu(ln1(x))) ----
__global__ __launch_bounds__(256) void prep_x_kernel(
        const float* __restrict__ X, const float* __restrict__ g,
        const float* __restrict__ b, unsigned short* __restrict__ Xh,
        unsigned short* __restrict__ Xl, unsigned short* __restrict__ A1) {
    int lane = threadIdx.x & 63;
    int n = (blockIdx.x << 2) + (threadIdx.x >> 6);
    const float* row = X + ((size_t)n << 9);
    float v[8]; float s = 0.f, ss = 0.f;
#pragma unroll
    for (int i = 0; i < 8; ++i) { v[i] = row[lane + (i << 6)]; s += v[i]; ss += v[i] * v[i]; }
    s = xorSum(s); ss = xorSum(ss);
    float mu = s * (1.f / 512.f);
    float rs = rsqrtf(ss * (1.f / 512.f) - mu * mu + 1e-5f);
#pragma unroll
    for (int i = 0; i < 8; ++i) {
        int c = lane + (i << 6);
        size_t o = ((size_t)n << 9) + c;
        float x = v[i];
        unsigned short h = f2bf(x);
        Xh[o] = h;
        Xl[o] = f2bf(x - bf2f(h));
        float a = fmaxf((x - mu) * rs * g[c] + b[c], 0.f);
        A1[o] = f2bf(a);
    }
}

// ---------------- prep: Hb(bf16) -> A2 = bf16(relu(ln2(h))) ----------------
__global__ __launch_bounds__(256) void prep_h_kernel(
        const unsigned short* __restrict__ Hb, const float* __restrict__ g,
        const float* __restrict__ b, unsigned short* __restrict__ A2) {
    int lane = threadIdx.x & 63;
    int n = (blockIdx.x << 2) + (threadIdx.x >> 6);
    const unsigned short* row = Hb + ((size_t)n << 9);
    float v[8]; float s = 0.f, ss = 0.f;
#pragma unroll
    for (int i = 0; i < 8; ++i) { v[i] = bf2f(row[lane + (i << 6)]); s += v[i]; ss += v[i] * v[i]; }
    s = xorSum(s); ss = xorSum(ss);
    float mu = s * (1.f / 512.f);
    float rs = rsqrtf(ss * (1.f / 512.f) - mu * mu + 1e-5f);
#pragma unroll
    for (int i = 0; i < 8; ++i) {
        int c = lane + (i << 6);
        float a = fmaxf((v[i] - mu) * rs * g[c] + b[c], 0.f);
        A2[((size_t)n << 9) + c] = f2bf(a);
    }
}

// ---------------- prep: E -> Eh,El + e_sq ----------------
__global__ __launch_bounds__(256) void prep_e_kernel(
        const float* __restrict__ E, unsigned short* __restrict__ Eh,
        unsigned short* __restrict__ El, float* __restrict__ e_sq) {
    int lane = threadIdx.x & 63;
    int m = (blockIdx.x << 2) + (threadIdx.x >> 6);
    const float* row = E + ((size_t)m << 9);
    float ss = 0.f;
#pragma unroll
    for (int i = 0; i < 8; ++i) {
        int c = lane + (i << 6);
        float x = row[c];
        ss += x * x;
        unsigned short h = f2bf(x);
        size_t o = ((size_t)m << 9) + c;
        Eh[o] = h;
        El[o] = f2bf(x - bf2f(h));
    }
    ss = xorSum(ss);
    if (lane == 0) e_sq[m] = ss;
}

// ---------------- prep: W[512][Nw] fp32 -> WT[Nw][512] bf16 ----------------
__global__ __launch_bounds__(256) void prep_wt_kernel(
        const float* __restrict__ W, unsigned short* __restrict__ WT, int Nw) {
    __shared__ float t[32][33];
    int n0 = blockIdx.x << 5, k0 = blockIdx.y << 5;
    int tx = threadIdx.x & 31, ty = threadIdx.x >> 5;
#pragma unroll
    for (int l = 0; l < 4; ++l)
        t[ty + (l << 3)][tx] = W[(size_t)(k0 + ty + (l << 3)) * Nw + n0 + tx];
    __syncthreads();
#pragma unroll
    for (int l = 0; l < 4; ++l)
        WT[(((size_t)(n0 + ty + (l << 3))) << 9) + k0 + tx] = f2bf(t[tx][ty + (l << 3)]);
}

// ---------------- distance MFMA (3-pass split) + fused argmin ----------------
__device__ __forceinline__ unsigned long long packDist(float d, int m) {
    unsigned u = __float_as_uint(d);
    u = (u & 0x80000000u) ? ~u : (u | 0x80000000u);
    return ((unsigned long long)u << 32) | (unsigned)m;
}

__global__ __launch_bounds__(256) void dist_mfma_kernel(
        const unsigned short* __restrict__ Xh, const unsigned short* __restrict__ Xl,
        const unsigned short* __restrict__ Eh, const unsigned short* __restrict__ El,
        const float* __restrict__ e_sq, unsigned long long* __restrict__ minpack) {
    __shared__ __align__(16) short Ah[4096], Al[4096], Bh[4096], Bl[4096];
    int tid = threadIdx.x, lane = tid & 63, w = tid >> 6;
    int quad = lane >> 4, lanelo = lane & 15;
    int wm = w >> 1, wn = w & 1;
    int row0 = blockIdx.x << 7, m0 = blockIdx.y << 7;
    f32x4 acc[4][4];
#pragma unroll
    for (int i = 0; i < 4; ++i)
#pragma unroll
        for (int j = 0; j < 4; ++j) acc[i][j] = 0.f;

    for (int k0 = 0; k0 < 512; k0 += 32) {
        stage_tile128(Xh, row0, k0, Ah, w, lane);
        stage_tile128(Xl, row0, k0, Al, w, lane);
        stage_tile128(Eh, m0, k0, Bh, w, lane);
        stage_tile128(El, m0, k0, Bl, w, lane);
        __syncthreads();
        short8 ah[4], alr[4], bh[4], blr[4];
#pragma unroll
        for (int i = 0; i < 4; ++i) {
            int m = (wm << 6) + (i << 4) + lanelo;
            ah[i]  = *(const short8*)&Ah[(quad << 10) + (m << 3)];
            alr[i] = *(const short8*)&Al[(quad << 10) + (m << 3)];
        }
#pragma unroll
        for (int j = 0; j < 4; ++j) {
            int n = (wn << 6) + (j << 4) + lanelo;
            bh[j]  = *(const short8*)&Bh[(quad << 10) + (n << 3)];
            blr[j] = *(const short8*)&Bl[(quad << 10) + (n << 3)];
        }
#pragma unroll
        for (int i = 0; i < 4; ++i)
#pragma unroll
            for (int j = 0; j < 4; ++j) {
                acc[i][j] = mfma16(ah[i],  bh[j],  acc[i][j]);
                acc[i][j] = mfma16(alr[i], bh[j],  acc[i][j]);
                acc[i][j] = mfma16(ah[i],  blr[j], acc[i][j]);
            }
        __syncthreads();
    }

    float esq[4];
#pragma unroll
    for (int j = 0; j < 4; ++j) esq[j] = e_sq[m0 + (wn << 6) + (j << 4) + lanelo];
#pragma unroll
    for (int i = 0; i < 4; ++i)
#pragma unroll
        for (int r = 0; r < 4; ++r) {
            unsigned long long best = ~0ULL;
#pragma unroll
            for (int j = 0; j < 4; ++j) {
                int code = m0 + (wn << 6) + (j << 4) + lanelo;
                float d = esq[j] - 2.f * acc[i][j][r];
                unsigned long long p = packDist(d, code);
                if (p < best) best = p;
            }
#pragma unroll
            for (int off = 1; off < 16; off <<= 1) {
                unsigned long long q = __shfl_xor(best, off);
                if (q < best) best = q;
            }
            if (lanelo == 0) {
                int t = row0 + (wm << 6) + (i << 4) + (quad << 2) + r;
                atomicMin(&minpack[t], best);
            }
        }
}

// ---------------- gather quantized + counts + vq term ----------------
__global__ __launch_bounds__(256) void gather_kernel(
        const float* __restrict__ X, const float* __restrict__ E,
        const unsigned long long* __restrict__ minpack,
        float* __restrict__ out_q, float* __restrict__ counts,
        float* __restrict__ vqsum) {
    int lane = threadIdx.x & 63;
    int n = (blockIdx.x << 2) + (threadIdx.x >> 6);
    int idx = (int)(minpack[n] & 0xFFFFFFFFULL);
    if (lane == 0) atomicAdd(&counts[idx], 1.0f);
    const float* xr = X + ((size_t)n << 9);
    const float* er = E + ((size_t)idx << 9);
    float s = 0.f;
#pragma unroll
    for (int i = 0; i < 8; ++i) {
        int c = lane + (i << 6);
        float xv = xr[c], q = er[c];
        out_q[((size_t)n << 9) + c] = q;
        float dlt = xv - q;
        s += dlt * dlt;
    }
    s = waveSum(s);
    if (lane == 0) vqsum[n] = 0.25f * s;
}

// ---------------- dw[m] = sum of x rows assigned to code m (no atomics) ----
__global__ __launch_bounds__(256) void dw_kernel(
        const float* __restrict__ X, const unsigned long long* __restrict__ minpack,
        float* __restrict__ dw) {
    __shared__ float acc[4][512];
    int tid = threadIdx.x, lane = tid & 63, w = tid >> 6;
    int m = blockIdx.x;
    for (int c = lane; c < 512; c += 64) acc[w][c] = 0.f;
    for (int n0 = (w << 13); n0 < ((w + 1) << 13); n0 += 64) {
        int idx = (int)(minpack[n0 + lane] & 0xFFFFFFFFULL);
        unsigned long long hit = __ballot(idx == m);
        while (hit) {
            int t = __ffsll((unsigned long long)hit) - 1;
            hit &= hit - 1;
            const float* xr = X + ((size_t)(n0 + t) << 9);
#pragma unroll
            for (int i = 0; i < 8; ++i) acc[w][lane + (i << 6)] += xr[lane + (i << 6)];
        }
    }
    __syncthreads();
    for (int c = tid; c < 512; c += 256)
        dw[((size_t)m << 9) + c] = acc[0][c] + acc[1][c] + acc[2][c] + acc[3][c];
}

// ---------------- GEMM1 MFMA: Hb = bf16(A1 @ W1T^T) ----------------
__global__ __launch_bounds__(256) void gemm1_mfma_kernel(
        const unsigned short* __restrict__ A1, const unsigned short* __restrict__ W1T,
        unsigned short* __restrict__ Hb) {
    __shared__ __align__(16) short As[4096], Bs[4096];
    int tid = threadIdx.x, lane = tid & 63, w = tid >> 6;
    int quad = lane >> 4, lanelo = lane & 15;
    int wm = w >> 1, wn = w & 1;
    int row0 = blockIdx.x << 7, n0 = blockIdx.y << 7;
    f32x4 acc[4][4];
#pragma unroll
    for (int i = 0; i < 4; ++i)
#pragma unroll
        for (int j = 0; j < 4; ++j) acc[i][j] = 0.f;

    for (int k0 = 0; k0 < 512; k0 += 32) {
        stage_tile128(A1, row0, k0, As, w, lane);
        stage_tile128(W1T, n0, k0, Bs, w, lane);
        __syncthreads();
        short8 af[4], bf[4];
#pragma unroll
        for (int i = 0; i < 4; ++i) {
            int m = (wm << 6) + (i << 4) + lanelo;
            af[i] = *(const short8*)&As[(quad << 10) + (m << 3)];
        }
#pragma unroll
        for (int j = 0; j < 4; ++j) {
            int n = (wn << 6) + (j << 4) + lanelo;
            bf[j] = *(const short8*)&Bs[(quad << 10) + (n << 3)];
        }
#pragma unroll
        for (int i = 0; i < 4; ++i)
#pragma unroll
            for (int j = 0; j < 4; ++j) acc[i][j] = mfma16(af[i], bf[j], acc[i][j]);
        __syncthreads();
    }
#pragma unroll
    for (int i = 0; i < 4; ++i)
#pragma unroll
        for (int j = 0; j < 4; ++j)
#pragma unroll
            for (int r = 0; r < 4; ++r) {
                int row = row0 + (wm << 6) + (i << 4) + (quad << 2) + r;
                int col = n0 + (wn << 6) + (j << 4) + lanelo;
                Hb[((size_t)row << 9) + col] = f2bf(acc[i][j][r]);
            }
}

// ---------------- GEMM2 chunk: 128 tokens x 128 codes, softmax partials ----
// ws layout [chunk][token] for coalesced writes here and coalesced reads in
// combine. Chunk max covers all 128 codes of this block -> exp(v-cm) <= 1.
__global__ __launch_bounds__(256) void gemm2_chunk_kernel(
        const unsigned short* __restrict__ A2, const unsigned short* __restrict__ W2T,
        const int* __restrict__ mask, const int* __restrict__ labels,
        float* __restrict__ ws_cmax, float* __restrict__ ws_csum,
        float* __restrict__ ws_lab) {
    __shared__ __align__(16) short As[4096], Bs[4096];
    __shared__ float lmax[2][2][64], lsum[2][2][64], llab[128];
    __shared__ int slab[128];
    int tid = threadIdx.x, lane = tid & 63, w = tid >> 6;
    int quad = lane >> 4, lanelo = lane & 15;
    int wm = w >> 1, wn = w & 1;
    int row0 = blockIdx.x << 7, c0 = blockIdx.y << 7;
    if (tid < 128) {
        int mk = mask[row0 + tid];
        slab[tid] = mk ? 0 : labels[row0 + tid];  // safe label
    }
    f32x4 acc[4][4];
#pragma unroll
    for (int i = 0; i < 4; ++i)
#pragma unroll
        for (int j = 0; j < 4; ++j) acc[i][j] = 0.f;

    for (int k0 = 0; k0 < 512; k0 += 32) {
        stage_tile128(A2, row0, k0, As, w, lane);
        stage_tile128(W2T, c0, k0, Bs, w, lane);
        __syncthreads();
        short8 af[4], bf[4];
#pragma unroll
        for (int i = 0; i < 4; ++i) {
            int m = (wm << 6) + (i << 4) + lanelo;
            af[i] = *(const short8*)&As[(quad << 10) + (m << 3)];
        }
#pragma unroll
        for (int j = 0; j < 4; ++j) {
            int n = (wn << 6) + (j << 4) + lanelo;
            bf[j] = *(const short8*)&Bs[(quad << 10) + (n << 3)];
        }
#pragma unroll
        for (int i = 0; i < 4; ++i)
#pragma unroll
            for (int j = 0; j < 4; ++j) acc[i][j] = mfma16(af[i], bf[j], acc[i][j]);
        __syncthreads();
    }

    // label-logit capture: each (token,code) pair has a unique owner lane/reg
#pragma unroll
    for (int i = 0; i < 4; ++i)
#pragma unroll
        for (int j = 0; j < 4; ++j)
#pragma unroll
            for (int r = 0; r < 4; ++r) {
                int code = c0 + (wn << 6) + (j << 4) + lanelo;
                int tt = (wm << 6) + (i << 4) + (quad << 2) + r;
                if (code == slab[tt]) llab[tt] = acc[i][j][r];
            }
    // per-wave, per-token max over this wave's 64 codes
#pragma unroll
    for (int i = 0; i < 4; ++i)
#pragma unroll
        for (int r = 0; r < 4; ++r) {
            float mx = fmaxf(fmaxf(acc[i][0][r], acc[i][1][r]),
                             fmaxf(acc[i][2][r], acc[i][3][r]));
#pragma unroll
            for (int off = 1; off < 16; off <<= 1) mx = fmaxf(mx, __shfl_xor(mx, off));
            if (lanelo == 0) lmax[wm][wn][(i << 4) + (quad << 2) + r] = mx;
        }
    __syncthreads();
    // sum-exp relative to the 128-code chunk max
#pragma unroll
    for (int i = 0; i < 4; ++i)
#pragma unroll
        for (int r = 0; r < 4; ++r) {
            int tl = (i << 4) + (quad << 2) + r;
            float cm = fmaxf(lmax[wm][0][tl], lmax[wm][1][tl]);
            float s = expf(acc[i][0][r] - cm) + expf(acc[i][1][r] - cm) +
                      expf(acc[i][2][r] - cm) + expf(acc[i][3][r] - cm);
#pragma unroll
            for (int off = 1; off < 16; off <<= 1) s += __shfl_xor(s, off);
            if (lanelo == 0) lsum[wm][wn][tl] = s;
        }
    __syncthreads();
    if (tid < 128) {
        int wmi = tid >> 6, tl = tid & 63;
        int token = row0 + tid;
        float cm = fmaxf(lmax[wmi][0][tl], lmax[wmi][1][tl]);
        float cs = lsum[wmi][0][tl] + lsum[wmi][1][tl];
        size_t o = ((size_t)blockIdx.y << 15) + token;  // [chunk][token]
        ws_cmax[o] = cm;
        ws_csum[o] = cs;
        if ((slab[tid] >> 7) == (int)blockIdx.y) ws_lab[token] = llab[tid];
    }
}

// ---------------- CE combine: logsumexp over 8 chunks + vq + mask ----------
__global__ __launch_bounds__(256) void ce_combine_kernel(
        const float* __restrict__ ws_cmax, const float* __restrict__ ws_csum,
        const float* __restrict__ ws_lab, const int* __restrict__ mask,
        const float* __restrict__ vqsum, float* __restrict__ loss_out) {
    int n = (blockIdx.x << 8) + threadIdx.x;
    float m[8], s[8];
#pragma unroll
    for (int c = 0; c < 8; ++c) {
        m[c] = ws_cmax[(c << 15) + n];
        s[c] = ws_csum[(c << 15) + n];
    }
    float gm = m[0];
#pragma unroll
    for (int c = 1; c < 8; ++c) gm = fmaxf(gm, m[c]);
    float se = 0.f;
#pragma unroll
    for (int c = 0; c < 8; ++c) se += s[c] * expf(m[c] - gm);
    float ce = -(ws_lab[n] - gm - logf(se));
    loss_out[n] = (mask[n] ? 0.f : ce) + vqsum[n];
}

// ---------------- EMA count smoothing + perplexity ----------------
__global__ __launch_bounds__(1024) void codebook_kernel(
        const float* __restrict__ ema_count, const float* __restrict__ counts,
        float* __restrict__ out_perp, float* __restrict__ out_newcount) {
    __shared__ float red[16];
    int tid = threadIdx.x;
    int lane = tid & 63, wid = tid >> 6;
    float cnt = counts[tid];
    float raw = 0.999f * ema_count[tid] + 0.001f * cnt;
    float v = waveSum(raw);
    if (lane == 0) red[wid] = v;
    __syncthreads();
    float nsum = 0.f;
#pragma unroll
    for (int i = 0; i < 16; ++i) nsum += red[i];
    __syncthreads();
    float p = cnt * (1.f / 32768.f);
    float e = p * logf(p + 1e-10f);
    e = waveSum(e);
    if (lane == 0) red[wid] = e;
    __syncthreads();
    float ent = 0.f;
#pragma unroll
    for (int i = 0; i < 16; ++i) ent += red[i];
    float nc = (raw + 1e-5f) / (nsum + 1024.f * 1e-5f) * nsum;
    out_newcount[tid] = nc;
    if (tid == 0) out_perp[0] = expf(-ent);
}

__global__ __launch_bounds__(256) void newweight_kernel(
        const float* __restrict__ ema_weight, const float* __restrict__ dw,
        const float* __restrict__ newcount, float* __restrict__ out_neww,
        float* __restrict__ out_newemb) {
    int i = (blockIdx.x << 8) + threadIdx.x;
    float nw = 0.999f * ema_weight[i] + 0.001f * dw[i];
    out_neww[i] = nw;
    out_newemb[i] = nw / newcount[i >> 9];
}

extern "C" void kernel_launch(void* const* d_in, const int* in_sizes, int n_in,
                              void* d_out, int out_size, void* d_ws, size_t ws_size,
                              hipStream_t stream) {
    const float* X          = (const float*)d_in[0];
    const int*   mask       = (const int*)d_in[1];
    const int*   labels     = (const int*)d_in[2];
    const float* E          = (const float*)d_in[3];
    const float* ema_count  = (const float*)d_in[4];
    const float* ema_weight = (const float*)d_in[5];
    const float* g1 = (const float*)d_in[6];
    const float* b1 = (const float*)d_in[7];
    const float* W1 = (const float*)d_in[8];
    const float* g2 = (const float*)d_in[9];
    const float* b2 = (const float*)d_in[10];
    const float* W2 = (const float*)d_in[11];

    float* out = (float*)d_out;
    float* out_q        = out;              // 16777216
    float* out_loss     = out + 16777216;   // 32768
    float* out_perp     = out + 16809984;   // 1
    float* out_newemb   = out + 16809985;   // 524288
    float* out_newcount = out + 17334273;   // 1024
    float* out_neww     = out + 17335297;   // 524288

    float* w = (float*)d_ws;
    float* vqsum = w;  w += 32768;
    float* e_sq = w;   w += 1024;
    float* counts = w; w += 1024;
    float* dwbuf = w;  w += 524288;
    unsigned long long* minpack = (unsigned long long*)w; w += 65536;
    float* ws_cmax = w; w += 262144;
    float* ws_csum = w; w += 262144;
    float* ws_lab  = w; w += 32768;
    unsigned short* Eh  = (unsigned short*)w; w += 262144;
    unsigned short* El  = (unsigned short*)w; w += 262144;
    unsigned short* W1T = (unsigned short*)w; w += 131072;
    unsigned short* W2T = (unsigned short*)w; w += 262144;
    unsigned short* Xh  = (unsigned short*)w; w += 8388608;
    unsigned short* Xl  = (unsigned short*)w; w += 8388608;
    unsigned short* A1  = (unsigned short*)w; w += 8388608;
    unsigned short* A2  = Xh;   // alias: Xh dead after dist
    unsigned short* Hb  = Xl;   // alias: Xl dead after dist

    hipMemsetAsync(counts, 0, 1024 * sizeof(float), stream);
    hipMemsetAsync(minpack, 0xFF, (size_t)N_TOK * sizeof(unsigned long long), stream);

    prep_e_kernel<<<256, 256, 0, stream>>>(E, Eh, El, e_sq);
    prep_wt_kernel<<<dim3(16, 16), 256, 0, stream>>>(W1, W1T, 512);
    prep_wt_kernel<<<dim3(32, 16), 256, 0, stream>>>(W2, W2T, 1024);
    prep_x_kernel<<<8192, 256, 0, stream>>>(X, g1, b1, Xh, Xl, A1);
    dist_mfma_kernel<<<dim3(256, 8), 256, 0, stream>>>(Xh, Xl, Eh, El, e_sq, minpack);
    gather_kernel<<<8192, 256, 0, stream>>>(X, E, minpack, out_q, counts, vqsum);
    dw_kernel<<<1024, 256, 0, stream>>>(X, minpack, dwbuf);
    gemm1_mfma_kernel<<<dim3(256, 4), 256, 0, stream>>>(A1, W1T, Hb);
    prep_h_kernel<<<8192, 256, 0, stream>>>(Hb, g2, b2, A2);
    gemm2_chunk_kernel<<<dim3(256, 8), 256, 0, stream>>>(A2, W2T, mask, labels,
                                                         ws_cmax, ws_csum, ws_lab);
    ce_combine_kernel<<<128, 256, 0, stream>>>(ws_cmax, ws_csum, ws_lab,
                                               mask, vqsum, out_loss);
    codebook_kernel<<<1, 1024, 0, stream>>>(ema_count, counts, out_perp, out_newcount);
    newweight_kernel<<<2048, 256, 0, stream>>>(ema_weight, dwbuf, out_newcount,
                                               out_neww, out_newemb);
}

// Round 4
// 490.966 us; speedup vs baseline: 3.0860x; 1.1172x over previous
//
#include <hip/hip_runtime.h>

// VQ-VAE forward on MI355X (gfx950). N=32768 tokens, D=512, M=1024, H=512.
// R4: (1) distance GEMM moved from bf16 3-pass to fp16 2-pass (X single fp16,
// E hi/lo fp16 scaled x512 -> error ~7e-6 on distances, ~fp32-class argmin);
// (2) dw scatter via bucketing (counts -> prefix -> token lists) instead of
// per-code full scans (33.5M serial loads eliminated).

#define N_TOK 32768

typedef __attribute__((ext_vector_type(8))) short short8;     // 8x16b = 4 VGPR
typedef _Float16 half8 __attribute__((ext_vector_type(8)));
typedef __attribute__((ext_vector_type(4))) float f32x4;

__device__ __forceinline__ f32x4 mfma16(short8 a, short8 b, f32x4 c) {
    return __builtin_amdgcn_mfma_f32_16x16x32_bf16(a, b, c, 0, 0, 0);
}
__device__ __forceinline__ f32x4 mfma16h(half8 a, half8 b, f32x4 c) {
    return __builtin_amdgcn_mfma_f32_16x16x32_f16(a, b, c, 0, 0, 0);
}

__device__ __forceinline__ void gl_lds16(const void* g, void* l) {
    __builtin_amdgcn_global_load_lds(
        (const __attribute__((address_space(1))) void*)g,
        (__attribute__((address_space(3))) void*)l, 16, 0, 0);
}

__device__ __forceinline__ unsigned short f2bf(float x) {   // RNE fp32->bf16
    unsigned u = __float_as_uint(x);
    u += 0x7fffu + ((u >> 16) & 1u);
    return (unsigned short)(u >> 16);
}
__device__ __forceinline__ float bf2f(unsigned short h) {
    return __uint_as_float(((unsigned)h) << 16);
}
__device__ __forceinline__ unsigned short f2h(float x) {    // RNE fp32->fp16
    union { _Float16 h; unsigned short u; } c;
    c.h = (_Float16)x;
    return c.u;
}
__device__ __forceinline__ float h2f(unsigned short u) {
    union { _Float16 h; unsigned short u; } c;
    c.u = u;
    return (float)c.h;
}

__device__ __forceinline__ float waveSum(float v) {
#pragma unroll
    for (int off = 32; off > 0; off >>= 1) v += __shfl_down(v, off, 64);
    return v;  // lane 0
}
__device__ __forceinline__ float xorSum(float v) {
#pragma unroll
    for (int off = 1; off < 64; off <<= 1) v += __shfl_xor(v, off);
    return v;  // all lanes
}

// Stage one 128x32 16-bit tile into LDS, chunk-swizzled layout [kb][128][8].
__device__ __forceinline__ void stage_tile128(const unsigned short* __restrict__ src,
                                              int r0, int k0, short* lds,
                                              int w, int lane) {
#pragma unroll
    for (int iss = 0; iss < 2; ++iss) {
        int L = (w << 11) + (iss << 10) + (lane << 4);  // byte offset in 8KB tile
        int kb = L >> 11, m = (L >> 4) & 127;
        gl_lds16(src + (((size_t)(r0 + m)) << 9) + k0 + (kb << 3), (char*)lds + L);
    }
}

// ---------------- prep: X -> Xf (fp16) + A1 = bf16(relu(ln1(x))) ----------
__global__ __launch_bounds__(256) void prep_x_kernel(
        const float* __restrict__ X, const float* __restrict__ g,
        const float* __restrict__ b, unsigned short* __restrict__ Xf,
        unsigned short* __restrict__ A1) {
    int lane = threadIdx.x & 63;
    int n = (blockIdx.x << 2) + (threadIdx.x >> 6);
    const float* row = X + ((size_t)n << 9);
    float v[8]; float s = 0.f, ss = 0.f;
#pragma unroll
    for (int i = 0; i < 8; ++i) { v[i] = row[lane + (i << 6)]; s += v[i]; ss += v[i] * v[i]; }
    s = xorSum(s); ss = xorSum(ss);
    float mu = s * (1.f / 512.f);
    float rs = rsqrtf(ss * (1.f / 512.f) - mu * mu + 1e-5f);
#pragma unroll
    for (int i = 0; i < 8; ++i) {
        int c = lane + (i << 6);
        size_t o = ((size_t)n << 9) + c;
        float x = v[i];
        Xf[o] = f2h(x);
        float a = fmaxf((x - mu) * rs * g[c] + b[c], 0.f);
        A1[o] = f2bf(a);
    }
}

// ---------------- prep: Hb(bf16) -> A2 = bf16(relu(ln2(h))) ----------------
__global__ __launch_bounds__(256) void prep_h_kernel(
        const unsigned short* __restrict__ Hb, const float* __restrict__ g,
        const float* __restrict__ b, unsigned short* __restrict__ A2) {
    int lane = threadIdx.x & 63;
    int n = (blockIdx.x << 2) + (threadIdx.x >> 6);
    const unsigned short* row = Hb + ((size_t)n << 9);
    float v[8]; float s = 0.f, ss = 0.f;
#pragma unroll
    for (int i = 0; i < 8; ++i) { v[i] = bf2f(row[lane + (i << 6)]); s += v[i]; ss += v[i] * v[i]; }
    s = xorSum(s); ss = xorSum(ss);
    float mu = s * (1.f / 512.f);
    float rs = rsqrtf(ss * (1.f / 512.f) - mu * mu + 1e-5f);
#pragma unroll
    for (int i = 0; i < 8; ++i) {
        int c = lane + (i << 6);
        float a = fmaxf((v[i] - mu) * rs * g[c] + b[c], 0.f);
        A2[((size_t)n << 9) + c] = f2bf(a);
    }
}

// ---------------- prep: E -> Ehf,Elf (fp16, scaled x512) + e_sq*512 --------
__global__ __launch_bounds__(256) void prep_e_kernel(
        const float* __restrict__ E, unsigned short* __restrict__ Ehf,
        unsigned short* __restrict__ Elf, float* __restrict__ e_sq) {
    int lane = threadIdx.x & 63;
    int m = (blockIdx.x << 2) + (threadIdx.x >> 6);
    const float* row = E + ((size_t)m << 9);
    float ss = 0.f;
#pragma unroll
    for (int i = 0; i < 8; ++i) {
        int c = lane + (i << 6);
        float x = row[c];
        ss += x * x;
        float xs = x * 512.f;           // exact pow2 scale, dodges fp16 subnormals
        unsigned short h = f2h(xs);
        size_t o = ((size_t)m << 9) + c;
        Ehf[o] = h;
        Elf[o] = f2h(xs - h2f(h));
    }
    ss = xorSum(ss);
    if (lane == 0) e_sq[m] = ss * 512.f;  // scaled to match 512*(x.e)
}

// ---------------- prep: W[512][Nw] fp32 -> WT[Nw][512] bf16 ----------------
__global__ __launch_bounds__(256) void prep_wt_kernel(
        const float* __restrict__ W, unsigned short* __restrict__ WT, int Nw) {
    __shared__ float t[32][33];
    int n0 = blockIdx.x << 5, k0 = blockIdx.y << 5;
    int tx = threadIdx.x & 31, ty = threadIdx.x >> 5;
#pragma unroll
    for (int l = 0; l < 4; ++l)
        t[ty + (l << 3)][tx] = W[(size_t)(k0 + ty + (l << 3)) * Nw + n0 + tx];
    __syncthreads();
#pragma unroll
    for (int l = 0; l < 4; ++l)
        WT[(((size_t)(n0 + ty + (l << 3))) << 9) + k0 + tx] = f2bf(t[tx][ty + (l << 3)]);
}

// ---------------- distance MFMA (fp16 2-pass) + fused argmin ----------------
// d' = 512*e_sq - 2*(Xf . (Ehf+Elf)) = 512*d  -> same argmin.
__device__ __forceinline__ unsigned long long packDist(float d, int m) {
    unsigned u = __float_as_uint(d);
    u = (u & 0x80000000u) ? ~u : (u | 0x80000000u);
    return ((unsigned long long)u << 32) | (unsigned)m;
}

__global__ __launch_bounds__(256) void dist_mfma_kernel(
        const unsigned short* __restrict__ Xf,
        const unsigned short* __restrict__ Ehf, const unsigned short* __restrict__ Elf,
        const float* __restrict__ e_sq, unsigned long long* __restrict__ minpack) {
    __shared__ __align__(16) short Axs[4096], Bh[4096], Bl[4096];
    int tid = threadIdx.x, lane = tid & 63, w = tid >> 6;
    int quad = lane >> 4, lanelo = lane & 15;
    int wm = w >> 1, wn = w & 1;
    int row0 = blockIdx.x << 7, m0 = blockIdx.y << 7;
    f32x4 acc[4][4];
#pragma unroll
    for (int i = 0; i < 4; ++i)
#pragma unroll
        for (int j = 0; j < 4; ++j) acc[i][j] = 0.f;

    for (int k0 = 0; k0 < 512; k0 += 32) {
        stage_tile128(Xf, row0, k0, Axs, w, lane);
        stage_tile128(Ehf, m0, k0, Bh, w, lane);
        stage_tile128(Elf, m0, k0, Bl, w, lane);
        __syncthreads();
        half8 av[4], bh[4], bl[4];
#pragma unroll
        for (int i = 0; i < 4; ++i) {
            int m = (wm << 6) + (i << 4) + lanelo;
            av[i] = __builtin_bit_cast(half8, *(const short8*)&Axs[(quad << 10) + (m << 3)]);
        }
#pragma unroll
        for (int j = 0; j < 4; ++j) {
            int n = (wn << 6) + (j << 4) + lanelo;
            bh[j] = __builtin_bit_cast(half8, *(const short8*)&Bh[(quad << 10) + (n << 3)]);
            bl[j] = __builtin_bit_cast(half8, *(const short8*)&Bl[(quad << 10) + (n << 3)]);
        }
#pragma unroll
        for (int i = 0; i < 4; ++i)
#pragma unroll
            for (int j = 0; j < 4; ++j) {
                acc[i][j] = mfma16h(av[i], bh[j], acc[i][j]);
                acc[i][j] = mfma16h(av[i], bl[j], acc[i][j]);
            }
        __syncthreads();
    }

    float esq[4];
#pragma unroll
    for (int j = 0; j < 4; ++j) esq[j] = e_sq[m0 + (wn << 6) + (j << 4) + lanelo];
#pragma unroll
    for (int i = 0; i < 4; ++i)
#pragma unroll
        for (int r = 0; r < 4; ++r) {
            unsigned long long best = ~0ULL;
#pragma unroll
            for (int j = 0; j < 4; ++j) {
                int code = m0 + (wn << 6) + (j << 4) + lanelo;
                float d = esq[j] - 2.f * acc[i][j][r];
                unsigned long long p = packDist(d, code);
                if (p < best) best = p;
            }
#pragma unroll
            for (int off = 1; off < 16; off <<= 1) {
                unsigned long long q = __shfl_xor(best, off);
                if (q < best) best = q;
            }
            if (lanelo == 0) {
                int t = row0 + (wm << 6) + (i << 4) + (quad << 2) + r;
                atomicMin(&minpack[t], best);
            }
        }
}

// ---------------- gather quantized + int counts + vq term ----------------
__global__ __launch_bounds__(256) void gather_kernel(
        const float* __restrict__ X, const float* __restrict__ E,
        const unsigned long long* __restrict__ minpack,
        float* __restrict__ out_q, int* __restrict__ icounts,
        float* __restrict__ vqsum) {
    int lane = threadIdx.x & 63;
    int n = (blockIdx.x << 2) + (threadIdx.x >> 6);
    int idx = (int)(minpack[n] & 0xFFFFFFFFULL);
    if (lane == 0) atomicAdd(&icounts[idx], 1);
    const float* xr = X + ((size_t)n << 9);
    const float* er = E + ((size_t)idx << 9);
    float s = 0.f;
#pragma unroll
    for (int i = 0; i < 8; ++i) {
        int c = lane + (i << 6);
        float xv = xr[c], q = er[c];
        out_q[((size_t)n << 9) + c] = q;
        float dlt = xv - q;
        s += dlt * dlt;
    }
    s = waveSum(s);
    if (lane == 0) vqsum[n] = 0.25f * s;
}

// ---------------- codebook: EMA smoothing + perplexity + bucket offsets ----
__global__ __launch_bounds__(1024) void codebook_kernel(
        const float* __restrict__ ema_count, const int* __restrict__ icounts,
        float* __restrict__ out_perp, float* __restrict__ out_newcount,
        int* __restrict__ offsets) {
    __shared__ int sc[1024];
    __shared__ float red[16];
    int tid = threadIdx.x;
    int lane = tid & 63, wid = tid >> 6;
    int ic = icounts[tid];
    sc[tid] = ic;
    // exclusive prefix (Hillis-Steele)
    for (int off = 1; off < 1024; off <<= 1) {
        __syncthreads();
        int v = (tid >= off) ? sc[tid - off] : 0;
        __syncthreads();
        sc[tid] += v;
    }
    offsets[tid] = sc[tid] - ic;
    __syncthreads();

    float cnt = (float)ic;
    float raw = 0.999f * ema_count[tid] + 0.001f * cnt;
    float v = waveSum(raw);
    if (lane == 0) red[wid] = v;
    __syncthreads();
    float nsum = 0.f;
#pragma unroll
    for (int i = 0; i < 16; ++i) nsum += red[i];
    __syncthreads();
    float p = cnt * (1.f / 32768.f);
    float e = p * logf(p + 1e-10f);
    e = waveSum(e);
    if (lane == 0) red[wid] = e;
    __syncthreads();
    float ent = 0.f;
#pragma unroll
    for (int i = 0; i < 16; ++i) ent += red[i];
    float nc = (raw + 1e-5f) / (nsum + 1024.f * 1e-5f) * nsum;
    out_newcount[tid] = nc;
    if (tid == 0) out_perp[0] = expf(-ent);
}

// ---------------- scatter: token n -> bucket of its code ----------------
__global__ __launch_bounds__(256) void scatter_kernel(
        const unsigned long long* __restrict__ minpack,
        const int* __restrict__ offsets, int* __restrict__ cursor,
        int* __restrict__ bucket) {
    int n = (blockIdx.x << 8) + threadIdx.x;
    int idx = (int)(minpack[n] & 0xFFFFFFFFULL);
    int pos = atomicAdd(&cursor[idx], 1);
    bucket[offsets[idx] + pos] = n;
}

// ---------------- dw[m] = sum of x rows in bucket m (dense reads) ----------
__global__ __launch_bounds__(256) void dw_kernel(
        const float* __restrict__ X, const int* __restrict__ bucket,
        const int* __restrict__ icounts, const int* __restrict__ offsets,
        float* __restrict__ dw) {
    __shared__ float comb[4][512];
    int tid = threadIdx.x, lane = tid & 63, w = tid >> 6;
    int m = blockIdx.x;
    int cnt = icounts[m], base = offsets[m];
    float acc[8] = {};
    for (int i = w; i < cnt; i += 4) {
        int t = bucket[base + i];
        const float* xr = X + ((size_t)t << 9);
#pragma unroll
        for (int j = 0; j < 8; ++j) acc[j] += xr[lane + (j << 6)];
    }
#pragma unroll
    for (int j = 0; j < 8; ++j) comb[w][lane + (j << 6)] = acc[j];
    __syncthreads();
    for (int c = tid; c < 512; c += 256)
        dw[((size_t)m << 9) + c] = comb[0][c] + comb[1][c] + comb[2][c] + comb[3][c];
}

// ---------------- GEMM1 MFMA: Hb = bf16(A1 @ W1T^T) ----------------
__global__ __launch_bounds__(256) void gemm1_mfma_kernel(
        const unsigned short* __restrict__ A1, const unsigned short* __restrict__ W1T,
        unsigned short* __restrict__ Hb) {
    __shared__ __align__(16) short As[4096], Bs[4096];
    int tid = threadIdx.x, lane = tid & 63, w = tid >> 6;
    int quad = lane >> 4, lanelo = lane & 15;
    int wm = w >> 1, wn = w & 1;
    int row0 = blockIdx.x << 7, n0 = blockIdx.y << 7;
    f32x4 acc[4][4];
#pragma unroll
    for (int i = 0; i < 4; ++i)
#pragma unroll
        for (int j = 0; j < 4; ++j) acc[i][j] = 0.f;

    for (int k0 = 0; k0 < 512; k0 += 32) {
        stage_tile128(A1, row0, k0, As, w, lane);
        stage_tile128(W1T, n0, k0, Bs, w, lane);
        __syncthreads();
        short8 af[4], bf[4];
#pragma unroll
        for (int i = 0; i < 4; ++i) {
            int m = (wm << 6) + (i << 4) + lanelo;
            af[i] = *(const short8*)&As[(quad << 10) + (m << 3)];
        }
#pragma unroll
        for (int j = 0; j < 4; ++j) {
            int n = (wn << 6) + (j << 4) + lanelo;
            bf[j] = *(const short8*)&Bs[(quad << 10) + (n << 3)];
        }
#pragma unroll
        for (int i = 0; i < 4; ++i)
#pragma unroll
            for (int j = 0; j < 4; ++j) acc[i][j] = mfma16(af[i], bf[j], acc[i][j]);
        __syncthreads();
    }
#pragma unroll
    for (int i = 0; i < 4; ++i)
#pragma unroll
        for (int j = 0; j < 4; ++j)
#pragma unroll
            for (int r = 0; r < 4; ++r) {
                int row = row0 + (wm << 6) + (i << 4) + (quad << 2) + r;
                int col = n0 + (wn << 6) + (j << 4) + lanelo;
                Hb[((size_t)row << 9) + col] = f2bf(acc[i][j][r]);
            }
}

// ---------------- GEMM2 chunk: 128 tokens x 128 codes, softmax partials ----
__global__ __launch_bounds__(256) void gemm2_chunk_kernel(
        const unsigned short* __restrict__ A2, const unsigned short* __restrict__ W2T,
        const int* __restrict__ mask, const int* __restrict__ labels,
        float* __restrict__ ws_cmax, float* __restrict__ ws_csum,
        float* __restrict__ ws_lab) {
    __shared__ __align__(16) short As[4096], Bs[4096];
    __shared__ float lmax[2][2][64], lsum[2][2][64], llab[128];
    __shared__ int slab[128];
    int tid = threadIdx.x, lane = tid & 63, w = tid >> 6;
    int quad = lane >> 4, lanelo = lane & 15;
    int wm = w >> 1, wn = w & 1;
    int row0 = blockIdx.x << 7, c0 = blockIdx.y << 7;
    if (tid < 128) {
        int mk = mask[row0 + tid];
        slab[tid] = mk ? 0 : labels[row0 + tid];  // safe label
    }
    f32x4 acc[4][4];
#pragma unroll
    for (int i = 0; i < 4; ++i)
#pragma unroll
        for (int j = 0; j < 4; ++j) acc[i][j] = 0.f;

    for (int k0 = 0; k0 < 512; k0 += 32) {
        stage_tile128(A2, row0, k0, As, w, lane);
        stage_tile128(W2T, c0, k0, Bs, w, lane);
        __syncthreads();
        short8 af[4], bf[4];
#pragma unroll
        for (int i = 0; i < 4; ++i) {
            int m = (wm << 6) + (i << 4) + lanelo;
            af[i] = *(const short8*)&As[(quad << 10) + (m << 3)];
        }
#pragma unroll
        for (int j = 0; j < 4; ++j) {
            int n = (wn << 6) + (j << 4) + lanelo;
            bf[j] = *(const short8*)&Bs[(quad << 10) + (n << 3)];
        }
#pragma unroll
        for (int i = 0; i < 4; ++i)
#pragma unroll
            for (int j = 0; j < 4; ++j) acc[i][j] = mfma16(af[i], bf[j], acc[i][j]);
        __syncthreads();
    }

    // label-logit capture (unique owner lane/reg)
#pragma unroll
    for (int i = 0; i < 4; ++i)
#pragma unroll
        for (int j = 0; j < 4; ++j)
#pragma unroll
            for (int r = 0; r < 4; ++r) {
                int code = c0 + (wn << 6) + (j << 4) + lanelo;
                int tt = (wm << 6) + (i << 4) + (quad << 2) + r;
                if (code == slab[tt]) llab[tt] = acc[i][j][r];
            }
#pragma unroll
    for (int i = 0; i < 4; ++i)
#pragma unroll
        for (int r = 0; r < 4; ++r) {
            float mx = fmaxf(fmaxf(acc[i][0][r], acc[i][1][r]),
                             fmaxf(acc[i][2][r], acc[i][3][r]));
#pragma unroll
            for (int off = 1; off < 16; off <<= 1) mx = fmaxf(mx, __shfl_xor(mx, off));
            if (lanelo == 0) lmax[wm][wn][(i << 4) + (quad << 2) + r] = mx;
        }
    __syncthreads();
#pragma unroll
    for (int i = 0; i < 4; ++i)
#pragma unroll
        for (int r = 0; r < 4; ++r) {
            int tl = (i << 4) + (quad << 2) + r;
            float cm = fmaxf(lmax[wm][0][tl], lmax[wm][1][tl]);
            float s = expf(acc[i][0][r] - cm) + expf(acc[i][1][r] - cm) +
                      expf(acc[i][2][r] - cm) + expf(acc[i][3][r] - cm);
#pragma unroll
            for (int off = 1; off < 16; off <<= 1) s += __shfl_xor(s, off);
            if (lanelo == 0) lsum[wm][wn][tl] = s;
        }
    __syncthreads();
    if (tid < 128) {
        int wmi = tid >> 6, tl = tid & 63;
        int token = row0 + tid;
        float cm = fmaxf(lmax[wmi][0][tl], lmax[wmi][1][tl]);
        float cs = lsum[wmi][0][tl] + lsum[wmi][1][tl];
        size_t o = ((size_t)blockIdx.y << 15) + token;  // [chunk][token]
        ws_cmax[o] = cm;
        ws_csum[o] = cs;
        if ((slab[tid] >> 7) == (int)blockIdx.y) ws_lab[token] = llab[tid];
    }
}

// ---------------- CE combine: logsumexp over 8 chunks + vq + mask ----------
__global__ __launch_bounds__(256) void ce_combine_kernel(
        const float* __restrict__ ws_cmax, const float* __restrict__ ws_csum,
        const float* __restrict__ ws_lab, const int* __restrict__ mask,
        const float* __restrict__ vqsum, float* __restrict__ loss_out) {
    int n = (blockIdx.x << 8) + threadIdx.x;
    float m[8], s[8];
#pragma unroll
    for (int c = 0; c < 8; ++c) {
        m[c] = ws_cmax[(c << 15) + n];
        s[c] = ws_csum[(c << 15) + n];
    }
    float gm = m[0];
#pragma unroll
    for (int c = 1; c < 8; ++c) gm = fmaxf(gm, m[c]);
    float se = 0.f;
#pragma unroll
    for (int c = 0; c < 8; ++c) se += s[c] * expf(m[c] - gm);
    float ce = -(ws_lab[n] - gm - logf(se));
    loss_out[n] = (mask[n] ? 0.f : ce) + vqsum[n];
}

__global__ __launch_bounds__(256) void newweight_kernel(
        const float* __restrict__ ema_weight, const float* __restrict__ dw,
        const float* __restrict__ newcount, float* __restrict__ out_neww,
        float* __restrict__ out_newemb) {
    int i = (blockIdx.x << 8) + threadIdx.x;
    float nw = 0.999f * ema_weight[i] + 0.001f * dw[i];
    out_neww[i] = nw;
    out_newemb[i] = nw / newcount[i >> 9];
}

extern "C" void kernel_launch(void* const* d_in, const int* in_sizes, int n_in,
                              void* d_out, int out_size, void* d_ws, size_t ws_size,
                              hipStream_t stream) {
    const float* X          = (const float*)d_in[0];
    const int*   mask       = (const int*)d_in[1];
    const int*   labels     = (const int*)d_in[2];
    const float* E          = (const float*)d_in[3];
    const float* ema_count  = (const float*)d_in[4];
    const float* ema_weight = (const float*)d_in[5];
    const float* g1 = (const float*)d_in[6];
    const float* b1 = (const float*)d_in[7];
    const float* W1 = (const float*)d_in[8];
    const float* g2 = (const float*)d_in[9];
    const float* b2 = (const float*)d_in[10];
    const float* W2 = (const float*)d_in[11];

    float* out = (float*)d_out;
    float* out_q        = out;              // 16777216
    float* out_loss     = out + 16777216;   // 32768
    float* out_perp     = out + 16809984;   // 1
    float* out_newemb   = out + 16809985;   // 524288
    float* out_newcount = out + 17334273;   // 1024
    float* out_neww     = out + 17335297;   // 524288

    float* w = (float*)d_ws;
    float* vqsum = w;  w += 32768;
    float* e_sq = w;   w += 1024;
    float* dwbuf = w;  w += 524288;
    unsigned long long* minpack = (unsigned long long*)w; w += 65536;
    float* ws_cmax = w; w += 262144;
    float* ws_csum = w; w += 262144;
    float* ws_lab  = w; w += 32768;
    int* icounts = (int*)w; w += 1024;      // icounts+cursor contiguous: one memset
    int* cursor  = (int*)w; w += 1024;
    int* offsets = (int*)w; w += 1024;
    int* bucket  = (int*)w; w += 32768;
    unsigned short* Ehf = (unsigned short*)w; w += 262144;
    unsigned short* Elf = (unsigned short*)w; w += 262144;
    unsigned short* W1T = (unsigned short*)w; w += 131072;
    unsigned short* W2T = (unsigned short*)w; w += 262144;
    unsigned short* Xf  = (unsigned short*)w; w += 8388608;
    unsigned short* A1  = (unsigned short*)w; w += 8388608;
    unsigned short* Hb  = (unsigned short*)w; w += 8388608;
    unsigned short* A2  = Xf;   // alias: Xf dead after dist

    hipMemsetAsync(icounts, 0, 2048 * sizeof(int), stream);
    hipMemsetAsync(minpack, 0xFF, (size_t)N_TOK * sizeof(unsigned long long), stream);

    prep_e_kernel<<<256, 256, 0, stream>>>(E, Ehf, Elf, e_sq);
    prep_wt_kernel<<<dim3(16, 16), 256, 0, stream>>>(W1, W1T, 512);
    prep_wt_kernel<<<dim3(32, 16), 256, 0, stream>>>(W2, W2T, 1024);
    prep_x_kernel<<<8192, 256, 0, stream>>>(X, g1, b1, Xf, A1);
    dist_mfma_kernel<<<dim3(256, 8), 256, 0, stream>>>(Xf, Ehf, Elf, e_sq, minpack);
    gather_kernel<<<8192, 256, 0, stream>>>(X, E, minpack, out_q, icounts, vqsum);
    codebook_kernel<<<1, 1024, 0, stream>>>(ema_count, icounts, out_perp,
                                            out_newcount, offsets);
    scatter_kernel<<<128, 256, 0, stream>>>(minpack, offsets, cursor, bucket);
    dw_kernel<<<1024, 256, 0, stream>>>(X, bucket, icounts, offsets, dwbuf);
    gemm1_mfma_kernel<<<dim3(256, 4), 256, 0, stream>>>(A1, W1T, Hb);
    prep_h_kernel<<<8192, 256, 0, stream>>>(Hb, g2, b2, A2);
    gemm2_chunk_kernel<<<dim3(256, 8), 256, 0, stream>>>(A2, W2T, mask, labels,
                                                         ws_cmax, ws_csum, ws_lab);
    ce_combine_kernel<<<128, 256, 0, stream>>>(ws_cmax, ws_csum, ws_lab,
                                               mask, vqsum, out_loss);
    newweight_kernel<<<2048, 256, 0, stream>>>(ema_weight, dwbuf, out_newcount,
                                               out_neww, out_newemb);
}